// Round 17
// baseline (118.801 us; speedup 1.0000x reference)
//
#include <hip/hip_runtime.h>

#define FF_N 4096

typedef __fp16 pkhalf2 __attribute__((ext_vector_type(2)));

__device__ __forceinline__ unsigned pack2(float a, float b) {
    union { pkhalf2 h; unsigned u; } cv;
    cv.h = __builtin_amdgcn_cvt_pkrtz(a, b);
    return cv.u;
}

// One slot-address macro serves every junction (f16-slot units):
//   writes: slot = WADDR(lane, reg); reads: slot = WADDR(reg, lane).
// Verified: b64 writes -> 16 distinct bank-pairs per rigid 16-lane group
// (pair = (q^t)&15); b16 reads -> 32 banks x 2 lanes sharing one dword
// (same-address, free); bijective on [0,4096).
__device__ __forceinline__ int WADDR(int a, int b) {
    return 64 * a + ((b & 3) | (((b >> 2) ^ (a & 15)) << 2));
}

// ---- in-register butterfly stages (all indices static after unroll) ----
__device__ __forceinline__ void bfly16(float v[64], const int base, const int stride) {
#pragma unroll
    for (int b = 1; b < 16; b <<= 1)
#pragma unroll
        for (int k = 0; k < 16; ++k)
            if (!(k & b)) {
                const float u = v[base + stride * k];
                const float w = v[base + stride * (k | b)];
                v[base + stride * k]       = u + w;
                v[base + stride * (k | b)] = u - w;
            }
}
__device__ __forceinline__ void bfly4(float v[64], const int base, const int stride) {
#pragma unroll
    for (int b = 1; b < 4; b <<= 1)
#pragma unroll
        for (int k = 0; k < 4; ++k)
            if (!(k & b)) {
                const float u = v[base + stride * k];
                const float w = v[base + stride * (k | b)];
                v[base + stride * k]       = u + w;
                v[base + stride * (k | b)] = u - w;
            }
}
// stage A: butterflies over d2 (reg stride 4) and d1h (reg stride 1 in quads)
__device__ __forceinline__ void stageA(float v[64]) {
#pragma unroll
    for (int lo = 0; lo < 4; ++lo) bfly16(v, lo, 4);
#pragma unroll
    for (int hi = 0; hi < 16; ++hi) bfly4(v, 4 * hi, 1);
}
// stage B: butterflies over d0 (reg stride 1) and d1l (reg stride 16)
__device__ __forceinline__ void stageB(float v[64]) {
#pragma unroll
    for (int g = 0; g < 4; ++g) bfly16(v, 16 * g, 1);
#pragma unroll
    for (int d = 0; d < 16; ++d) bfly4(v, d, 16);
}

// Per-launch precompute:
//  gaT2[64*(k&63) + (k>>6)] = { W2-slot of FWHT1-element perm[k], bits(diag_g[k]) }
//  (transposed so the kernel's gather-table reads are dense), ss2 = diag_s/8.
__global__ void ff_setup(const float* __restrict__ diag_s,
                         const float* __restrict__ diag_g,
                         const int*   __restrict__ perm,
                         int2*  __restrict__ gaT2,
                         float* __restrict__ ss2) {
    const int k = blockIdx.x * 256 + threadIdx.x;
    const int p = perm[k];
    int2 e;
    e.x = WADDR(p >> 6, p & 63);          // slot where element p was staged
    e.y = __float_as_int(diag_g[k]);
    gaT2[((k & 63) << 6) | (k >> 6)] = e;
    ss2[k] = diag_s[k] * 0.125f;
}

// ONE WAVE PER ROW, 64 f32/lane, ZERO barriers: all junction exchanges are
// intra-wave (per-wave DS ops execute in order; compiler preserves aliasing
// LDS write->read order). FWHT1 = stageA -> J1 -> stageB; gather; FWHT2 =
// stageB' -> J3 -> stageA'. Load/store/table reads all dense-coalesced.
// Normalization 1/4096 = (1/8)^3 at the three stagings x (1/8) in ss2.
__global__ __launch_bounds__(64) void fastfood_wave_kernel(
    const float* __restrict__ x,
    const float* __restrict__ diag_b,
    const int2*  __restrict__ gaT2,
    const float* __restrict__ ss2,
    float* __restrict__ out)
{
    __shared__ __align__(16) __fp16 H[FF_N];   // 8 KB -> 20 blocks/CU
    const int t = threadIdx.x;
    const size_t row = blockIdx.x;
    const float* __restrict__ xr   = x   + row * (size_t)FF_N;
    float* __restrict__       outr = out + row * (size_t)FF_N;

    float v[64];

    // ---- load * diag_b: e = 64r + t (dense per instruction) ----
#pragma unroll
    for (int r = 0; r < 64; ++r) {
        const int e = 64 * r + t;
        v[r] = xr[e] * diag_b[e];
    }

    stageA(v);   // FWHT1 bits 6-11

    // ---- J1 write (x 1/8): b64 per q, slots WADDR(t, 4q..4q+3) ----
#pragma unroll
    for (int q = 0; q < 16; ++q) {
        const int sB = 64 * t + ((q ^ (t & 15)) << 2);
        uint2 w;
        w.x = pack2(v[4 * q + 0] * 0.125f, v[4 * q + 1] * 0.125f);
        w.y = pack2(v[4 * q + 2] * 0.125f, v[4 * q + 3] * 0.125f);
        *(uint2*)&H[sB] = w;
    }
    // ---- J1 read: v[r] = H[WADDR(r, t)] ----
#pragma unroll
    for (int r = 0; r < 64; ++r)
        v[r] = (float)H[WADDR(r, t)];

    stageB(v);   // FWHT1 bits 0-5 -> FWHT1 done

    // ---- W2 write (x 1/8): same write macro (in-order DS: J1 reads precede) ----
#pragma unroll
    for (int q = 0; q < 16; ++q) {
        const int sB = 64 * t + ((q ^ (t & 15)) << 2);
        uint2 w;
        w.x = pack2(v[4 * q + 0] * 0.125f, v[4 * q + 1] * 0.125f);
        w.y = pack2(v[4 * q + 2] * 0.125f, v[4 * q + 3] * 0.125f);
        *(uint2*)&H[sB] = w;
    }
    // ---- gather: dense int2 table {slot, g}; v[r] = H[slot] * g ----
#pragma unroll
    for (int r = 0; r < 64; ++r) {
        const int2 ag = gaT2[64 * r + t];
        v[r] = (float)H[ag.x] * __int_as_float(ag.y);
    }

    stageB(v);   // FWHT2 bits 0-5

    // ---- J3 write (x 1/8) ----
#pragma unroll
    for (int q = 0; q < 16; ++q) {
        const int sB = 64 * t + ((q ^ (t & 15)) << 2);
        uint2 w;
        w.x = pack2(v[4 * q + 0] * 0.125f, v[4 * q + 1] * 0.125f);
        w.y = pack2(v[4 * q + 2] * 0.125f, v[4 * q + 3] * 0.125f);
        *(uint2*)&H[sB] = w;
    }
    // ---- J3 read ----
#pragma unroll
    for (int r = 0; r < 64; ++r)
        v[r] = (float)H[WADDR(r, t)];

    stageA(v);   // FWHT2 bits 6-11

    // ---- store: e = 64r + t (dense), * diag_s/8, nontemporal ----
#pragma unroll
    for (int r = 0; r < 64; ++r) {
        const int e = 64 * r + t;
        __builtin_nontemporal_store(v[r] * ss2[e], &outr[e]);
    }
}

extern "C" void kernel_launch(void* const* d_in, const int* in_sizes, int n_in,
                              void* d_out, int out_size, void* d_ws, size_t ws_size,
                              hipStream_t stream) {
    const float* x      = (const float*)d_in[0];
    const float* diag_s = (const float*)d_in[1];
    const float* diag_g = (const float*)d_in[2];
    const float* diag_b = (const float*)d_in[3];
    const int*   perm   = (const int*)d_in[4];
    float* out = (float*)d_out;

    int2*  gaT2 = (int2*)d_ws;                       // 32 KB
    float* ss2  = (float*)((char*)d_ws + FF_N * 8);  // 16 KB

    ff_setup<<<FF_N / 256, 256, 0, stream>>>(diag_s, diag_g, perm, gaT2, ss2);

    const int batch = in_sizes[0] / FF_N;   // 16384 rows
    fastfood_wave_kernel<<<batch, 64, 0, stream>>>(x, diag_b, gaT2, ss2, out);
}

// Round 18
// 90.497 us; speedup vs baseline: 1.3128x; 1.3128x over previous
//
#include <hip/hip_runtime.h>

#define FF_N 4096
#define S64  0.015625f   // 1/64 per FWHT (total 1/4096)

typedef float  v2f __attribute__((ext_vector_type(2)));
typedef __fp16 pkhalf2 __attribute__((ext_vector_type(2)));

// Packed fp32 (VOP3P) — both rows' butterfly op in one instruction.
__device__ __forceinline__ v2f pk_add(v2f a, v2f b) {
    v2f d; asm("v_pk_add_f32 %0, %1, %2" : "=v"(d) : "v"(a), "v"(b)); return d;
}
__device__ __forceinline__ v2f pk_sub(v2f a, v2f b) {
    v2f d; asm("v_pk_add_f32 %0, %1, %2 neg_lo:[0,1] neg_hi:[0,1]"
               : "=v"(d) : "v"(a), "v"(b)); return d;
}
__device__ __forceinline__ void h16p(v2f v[16]) {
#pragma unroll
    for (int b = 1; b < 16; b <<= 1) {
#pragma unroll
        for (int r = 0; r < 16; ++r) {
            if ((r & b) == 0) {
                const v2f u = v[r], w = v[r | b];
                v[r]     = pk_add(u, w);
                v[r | b] = pk_sub(u, w);
            }
        }
    }
}

// f16x2 pack/unpack: one LDS dword holds both rows' same element.
__device__ __forceinline__ unsigned pkpack(v2f a) {
    union { pkhalf2 h; unsigned u; } cv;
    cv.h = __builtin_amdgcn_cvt_pkrtz(a[0], a[1]);
    return cv.u;
}
__device__ __forceinline__ v2f pkunpack(unsigned u) {
    union { unsigned u; pkhalf2 h; } cv; cv.u = u;
    return (v2f){(float)cv.h[0], (float)cv.h[1]};
}

// Layouts (bijective, conflict-free under the R8-validated rigid-group model):
//  A: aA = (d2<<8)|((d1>>3)<<7)|((d0>>2)<<5)|(((d1&7)^(d0>>2))<<2)|(d0&3)
//  P: aP = (d2<<8)|((d0>>3)<<7)|((d1>>2)<<5)|(((d0&7)^(d1>>2))<<2)|(d1&3)
//  W: aW = (d1<<8)|((d0>>3)<<7)|((d2>>2)<<5)|(((d0&7)^(d2>>2))<<2)|(d2&3)
// Shared write base WB[q] = (T<<8)|((c>>3)<<7)|(q<<5)|(((c&7)^q)<<2).
// Ping-pong LDS buffers L0/L1 remove the 4 WAR barriers -> 5 barriers total.

__global__ void ff_setup(const float* __restrict__ diag_s,
                         const float* __restrict__ diag_g,
                         const int*   __restrict__ perm,
                         int*   __restrict__ gaddr,
                         float* __restrict__ gg,
                         float* __restrict__ ss) {
    const int k   = blockIdx.x * 256 + threadIdx.x;
    const int pe  = perm[k];
    const int d2p = pe >> 8, d1p = (pe >> 4) & 15, d0p = pe & 15;
    gaddr[k] = (d1p << 8) | ((d0p >> 3) << 7) | ((d2p >> 2) << 5)
             | (((d0p & 7) ^ (d2p >> 2)) << 2) | (d2p & 3);
    gg[k] = diag_g[k] * S64;
    ss[k] = diag_s[k] * S64;
}

__global__ __launch_bounds__(256) void fastfood_db_kernel(
    const float* __restrict__ x,
    const float* __restrict__ diag_b,
    const int*   __restrict__ gaddr,
    const float* __restrict__ gg,
    const float* __restrict__ ss,
    float* __restrict__ out)
{
    __shared__ __align__(16) unsigned L0[FF_N];   // 16 KB (f16x2-packed pairs)
    __shared__ __align__(16) unsigned L1[FF_N];   // 16 KB (ping-pong partner)
    const int t = threadIdx.x;
    const int T = t >> 4, c = t & 15;
    const size_t rowA = (size_t)blockIdx.x * 2;
    const float* __restrict__ xA   = x   + rowA * FF_N;
    const float* __restrict__ xB   = xA  + FF_N;
    float* __restrict__       outA = out + rowA * FF_N;
    float* __restrict__       outB = outA + FF_N;

    // shared write bases (A-, P-, W-writes all use the same formula)
    int WB[4];
#pragma unroll
    for (int q = 0; q < 4; ++q)
        WB[q] = (T << 8) | ((c >> 3) << 7) | (q << 5) | (((c & 7) ^ q) << 2);
    const int AR0 = (T << 8) | ((c >> 2) << 5) | (c & 3);           // A-read base
    const int PR0 = ((c >> 3) << 7) | ((T >> 2) << 5)
                  | (((c & 7) ^ (T >> 2)) << 2) | (T & 3);          // P-read base

    v2f v[16];

#define JWRITE(Lbuf)                                                           \
    {                                                                          \
        _Pragma("unroll")                                                      \
        for (int q = 0; q < 4; ++q) {                                          \
            uint4 w;                                                           \
            w.x = pkpack(v[4 * q + 0]); w.y = pkpack(v[4 * q + 1]);            \
            w.z = pkpack(v[4 * q + 2]); w.w = pkpack(v[4 * q + 3]);            \
            *(uint4*)&(Lbuf)[WB[q]] = w;                                       \
        }                                                                      \
    }

    // ===== P1: load both rows * diag_b (float4, coalesced); h16(d0); A-write L0 =====
    {
        const float4* __restrict__ xa4 = (const float4*)(xA + 16 * t);
        const float4* __restrict__ xb4 = (const float4*)(xB + 16 * t);
        const float4* __restrict__ b4  = (const float4*)(diag_b + 16 * t);
#pragma unroll
        for (int q = 0; q < 4; ++q) {
            const float4 bv = b4[q];
            const float4 av = xa4[q];
            const float4 wv = xb4[q];
            v[4 * q + 0] = (v2f){av.x * bv.x, wv.x * bv.x};
            v[4 * q + 1] = (v2f){av.y * bv.y, wv.y * bv.y};
            v[4 * q + 2] = (v2f){av.z * bv.z, wv.z * bv.z};
            v[4 * q + 3] = (v2f){av.w * bv.w, wv.w * bv.w};
        }
        h16p(v);
        JWRITE(L0);
    }
    __syncthreads();   // B1: L0 ready

    // ===== P2: A-read L0 (all d1); h16(d1); P-write L1 =====
#pragma unroll
    for (int j = 0; j < 16; ++j)
        v[j] = pkunpack(L0[AR0 | ((j >> 3) << 7) | (((j & 7) ^ (c >> 2)) << 2)]);
    h16p(v);
    JWRITE(L1);
    __syncthreads();   // B2: L1 ready (and all L0 reads done)

    // ===== P3: P-read L1 (all d2); h16(d2) -> FWHT1 done; W-write L0 =====
#pragma unroll
    for (int j = 0; j < 16; ++j) v[j] = pkunpack(L1[PR0 | (j << 8)]);
    h16p(v);
    JWRITE(L0);
    __syncthreads();   // B3: L0 (gather source) ready

    // ===== P4: precomputed gather L0 * gg; h16(d0'); A-write L1 =====
    {
        const int4*   __restrict__ ga4 = (const int4*)(gaddr + 16 * t);
        const float4* __restrict__ gg4 = (const float4*)(gg + 16 * t);
#pragma unroll
        for (int q = 0; q < 4; ++q) {
            const int4   pa = ga4[q];
            const float4 gv = gg4[q];
            const v2f a0 = pkunpack(L0[pa.x]), a1 = pkunpack(L0[pa.y]);
            const v2f a2 = pkunpack(L0[pa.z]), a3 = pkunpack(L0[pa.w]);
            v[4 * q + 0] = (v2f){a0[0] * gv.x, a0[1] * gv.x};
            v[4 * q + 1] = (v2f){a1[0] * gv.y, a1[1] * gv.y};
            v[4 * q + 2] = (v2f){a2[0] * gv.z, a2[1] * gv.z};
            v[4 * q + 3] = (v2f){a3[0] * gv.w, a3[1] * gv.w};
        }
        h16p(v);
    }
    JWRITE(L1);
    __syncthreads();   // B4: L1 ready (and all L0 gather reads done)

    // ===== P5: A-read L1; h16(d1'); P-write L0 =====
#pragma unroll
    for (int j = 0; j < 16; ++j)
        v[j] = pkunpack(L1[AR0 | ((j >> 3) << 7) | (((j & 7) ^ (c >> 2)) << 2)]);
    h16p(v);
    JWRITE(L0);
    __syncthreads();   // B5: L0 ready

    // ===== P6: P-read L0; h16(d2'); DENSE NT store out[256j + t] * ss =====
#pragma unroll
    for (int j = 0; j < 16; ++j) v[j] = pkunpack(L0[PR0 | (j << 8)]);
    h16p(v);
#pragma unroll
    for (int j = 0; j < 16; ++j) {
        const int e = 256 * j + t;
        const float s = ss[e];
        __builtin_nontemporal_store(v[j][0] * s, &outA[e]);
        __builtin_nontemporal_store(v[j][1] * s, &outB[e]);
    }
#undef JWRITE
}

extern "C" void kernel_launch(void* const* d_in, const int* in_sizes, int n_in,
                              void* d_out, int out_size, void* d_ws, size_t ws_size,
                              hipStream_t stream) {
    const float* x      = (const float*)d_in[0];
    const float* diag_s = (const float*)d_in[1];
    const float* diag_g = (const float*)d_in[2];
    const float* diag_b = (const float*)d_in[3];
    const int*   perm   = (const int*)d_in[4];
    float* out = (float*)d_out;

    int*   gaddr = (int*)d_ws;
    float* gg    = (float*)d_ws + FF_N;
    float* ss    = (float*)d_ws + 2 * FF_N;

    ff_setup<<<FF_N / 256, 256, 0, stream>>>(diag_s, diag_g, perm, gaddr, gg, ss);

    const int batch = in_sizes[0] / FF_N;   // 16384 rows
    fastfood_db_kernel<<<batch / 2, 256, 0, stream>>>(x, diag_b, gaddr, gg, ss, out);
}